// Round 5
// baseline (123.635 us; speedup 1.0000x reference)
//
#include <hip/hip_runtime.h>
#include <math.h>

// B=4, N=512, C=D=256, K=20, rows=2048
//
// ws layout (float offsets):
//   WtL   [0, 65536)         W_l^T [c][d]
//   WtR   [65536, 131072)
//   XL    [1048576, +524288) [row][d]  row-major
//   XRt   [1572864, +524288) [b][d][j] d-major
//   Av    [2097152, +2048)   dot(att, XL[row])
//   Bv    [2099200, +2048)   dot(att, XR[row])
//
// out (float): [0,40960) index_i | [40960,81920) index_j | [81920,122880) attention

__global__ __launch_bounds__(256) void k_transpose(const float* __restrict__ Wl,
                                                   const float* __restrict__ Wr,
                                                   float* __restrict__ WtL,
                                                   float* __restrict__ WtR) {
    const int d = blockIdx.x, c = threadIdx.x;  // coalesced read of W[d][:]
    if (blockIdx.y == 0) WtL[c * 256 + d] = Wl[d * 256 + c];
    else                 WtR[c * 256 + d] = Wr[d * 256 + c];
}

// 256 wgs x 1024 thr; wg = 8 rows, c-split 4 (ch = tid>>8 owns 64 c-values).
// 16 waves/CU = 4 waves/SIMD. Wt traffic: 256 wgs * 512 KB = 128 MB (halved).
__global__ __launch_bounds__(1024) void k_proj(const float* __restrict__ x,
        const float* __restrict__ WtL, const float* __restrict__ WtR,
        const float* __restrict__ bl, const float* __restrict__ br,
        const float* __restrict__ att,
        float* __restrict__ XL, float* __restrict__ XRt,
        float* __restrict__ Av, float* __restrict__ Bv) {
    __shared__ float xs[8 * 256];          // 8 KB
    __shared__ float mrg[3 * 16 * 256];    // 48 KB: ch=1..3 partials [(ch-1)][r*2+side][d]
    __shared__ float red[64];
    const int tid = threadIdx.x;
    const int d = tid & 255;
    const int ch = tid >> 8;               // 0..3 (wave-uniform)
    const int R = blockIdx.x * 8;

    if (tid < 512) ((float4*)xs)[tid] = ((const float4*)(x + (size_t)R * 256))[tid];
    __syncthreads();

    float accL[8] = {0.f,0.f,0.f,0.f,0.f,0.f,0.f,0.f};
    float accR[8] = {0.f,0.f,0.f,0.f,0.f,0.f,0.f,0.f};
    const int c0 = ch * 64;
    for (int cq = 0; cq < 16; ++cq) {
        const int c = c0 + cq * 4;
        const float wl0 = WtL[(c + 0) * 256 + d];
        const float wl1 = WtL[(c + 1) * 256 + d];
        const float wl2 = WtL[(c + 2) * 256 + d];
        const float wl3 = WtL[(c + 3) * 256 + d];
        const float wr0 = WtR[(c + 0) * 256 + d];
        const float wr1 = WtR[(c + 1) * 256 + d];
        const float wr2 = WtR[(c + 2) * 256 + d];
        const float wr3 = WtR[(c + 3) * 256 + d];
#pragma unroll
        for (int r = 0; r < 8; ++r) {
            const float4 xv = *(const float4*)&xs[r * 256 + c];  // LDS broadcast
            accL[r] = fmaf(xv.x, wl0, accL[r]);
            accL[r] = fmaf(xv.y, wl1, accL[r]);
            accL[r] = fmaf(xv.z, wl2, accL[r]);
            accL[r] = fmaf(xv.w, wl3, accL[r]);
            accR[r] = fmaf(xv.x, wr0, accR[r]);
            accR[r] = fmaf(xv.y, wr1, accR[r]);
            accR[r] = fmaf(xv.z, wr2, accR[r]);
            accR[r] = fmaf(xv.w, wr3, accR[r]);
        }
    }

    if (ch != 0) {
        float* m = &mrg[(ch - 1) * 4096];
#pragma unroll
        for (int r = 0; r < 8; ++r) {
            m[(r * 2 + 0) * 256 + d] = accL[r];   // lane d consecutive: conflict-free
            m[(r * 2 + 1) * 256 + d] = accR[r];
        }
    }
    __syncthreads();

    if (ch == 0) {
        const float blv = bl[d], brv = br[d], atv = att[d];
        const int b = R >> 9, jr = R & 511;
        float pa[8], pb[8], xrq[8];
#pragma unroll
        for (int r = 0; r < 8; ++r) {
            const int iL = (r * 2 + 0) * 256 + d;
            const int iR = (r * 2 + 1) * 256 + d;
            const float sl = accL[r] + mrg[iL] + mrg[4096 + iL] + mrg[8192 + iL] + blv;
            const float sr = accR[r] + mrg[iR] + mrg[4096 + iR] + mrg[8192 + iR] + brv;
            XL[(size_t)(R + r) * 256 + d] = sl;   // coalesced
            xrq[r] = sr;
            pa[r] = atv * sl;
            pb[r] = atv * sr;
        }
        *(float4*)&XRt[((size_t)(b * 256 + d)) * 512 + jr] =
            make_float4(xrq[0], xrq[1], xrq[2], xrq[3]);
        *(float4*)&XRt[((size_t)(b * 256 + d)) * 512 + jr + 4] =
            make_float4(xrq[4], xrq[5], xrq[6], xrq[7]);
#pragma unroll
        for (int r = 0; r < 8; ++r) {
#pragma unroll
            for (int off = 32; off; off >>= 1) {
                pa[r] += __shfl_xor(pa[r], off);
                pb[r] += __shfl_xor(pb[r], off);
            }
        }
        const int lane = tid & 63, wv = tid >> 6;  // wv 0..3
        if (lane == 0) {
#pragma unroll
            for (int r = 0; r < 8; ++r) {
                red[r * 8 + wv] = pa[r];
                red[r * 8 + 4 + wv] = pb[r];
            }
        }
    }
    __syncthreads();
    if (tid < 16) {
        const int r = tid >> 1, side = tid & 1;
        const float* p = &red[r * 8 + side * 4];
        const float s = p[0] + p[1] + p[2] + p[3];
        if (side == 0) Av[R + r] = s; else Bv[R + r] = s;
    }
}

// Fused pair + top-k + softmax. 1024 wgs x 256 thr; wg = 2 rows x 512 j.
// Thread: jc = tid&127 (4 j), h = tid>>7 (d-half). 4 wg/CU = 4 waves/SIMD.
__global__ __launch_bounds__(256, 4) void k_pair_topk(const float* __restrict__ XL,
        const float* __restrict__ XRt, const float* __restrict__ Av,
        const float* __restrict__ Bv, const float* __restrict__ att,
        float* __restrict__ out) {
    __shared__ float xls[2 * 256];
    __shared__ float atts[256];
    __shared__ float mrg[8 * 128];    // [i*4+c][jc] h=1 partials
    __shared__ float alph[2 * 512];
    const int tid = threadIdx.x;
    const int g = blockIdx.x;          // 0..1023 = row-pair
    const int R = g * 2;
    const int b = R >> 9;
    const int jc = tid & 127;
    const int h = tid >> 7;            // wave-uniform d-half

    if (tid < 128)      ((float4*)xls)[tid] = ((const float4*)(XL + (size_t)R * 256))[tid];
    else if (tid < 192) ((float4*)atts)[tid - 128] = ((const float4*)att)[tid - 128];
    __syncthreads();

    const float* xrbase = XRt + ((size_t)(b * 256 + h * 128)) * 512 + jc * 4;
    const int dbase = h * 128;

    float4 acc[2];
    acc[0] = make_float4(0.f, 0.f, 0.f, 0.f);
    acc[1] = make_float4(0.f, 0.f, 0.f, 0.f);

    float4 buf[2][8];
#pragma unroll
    for (int dd = 0; dd < 8; ++dd) buf[0][dd] = *(const float4*)(xrbase + dd * 512);

#pragma unroll
    for (int ch = 0; ch < 16; ++ch) {
        const float4* cur = buf[ch & 1];
        float4* nxt = buf[(ch + 1) & 1];
        if (ch < 15) {
            const float* p = xrbase + (size_t)(ch + 1) * 8 * 512;
#pragma unroll
            for (int dd = 0; dd < 8; ++dd) nxt[dd] = *(const float4*)(p + dd * 512);
        }
        const int d = dbase + ch * 8;
        const float4 at0 = *(const float4*)&atts[d];       // LDS broadcast
        const float4 at1 = *(const float4*)&atts[d + 4];
#pragma unroll
        for (int i = 0; i < 2; ++i) {
            const float4 xa = *(const float4*)&xls[i * 256 + d];
            const float4 xb = *(const float4*)&xls[i * 256 + d + 4];
#define PSTEP(XLC, ATC, XR4)                                   \
            acc[i].x = fmaf(ATC, fabsf(XLC + XR4.x), acc[i].x); \
            acc[i].y = fmaf(ATC, fabsf(XLC + XR4.y), acc[i].y); \
            acc[i].z = fmaf(ATC, fabsf(XLC + XR4.z), acc[i].z); \
            acc[i].w = fmaf(ATC, fabsf(XLC + XR4.w), acc[i].w);
            PSTEP(xa.x, at0.x, cur[0])
            PSTEP(xa.y, at0.y, cur[1])
            PSTEP(xa.z, at0.z, cur[2])
            PSTEP(xa.w, at0.w, cur[3])
            PSTEP(xb.x, at1.x, cur[4])
            PSTEP(xb.y, at1.y, cur[5])
            PSTEP(xb.z, at1.z, cur[6])
            PSTEP(xb.w, at1.w, cur[7])
#undef PSTEP
        }
    }

    if (h == 1) {
#pragma unroll
        for (int i = 0; i < 2; ++i) {
            mrg[(i * 4 + 0) * 128 + jc] = acc[i].x;
            mrg[(i * 4 + 1) * 128 + jc] = acc[i].y;
            mrg[(i * 4 + 2) * 128 + jc] = acc[i].z;
            mrg[(i * 4 + 3) * 128 + jc] = acc[i].w;
        }
    }
    __syncthreads();
    if (h == 0) {
        const float4 Bj = *(const float4*)&Bv[b * 512 + jc * 4];
#pragma unroll
        for (int i = 0; i < 2; ++i) {
            const float Ai = Av[R + i];
            float a0 = fmaf(0.4f, acc[i].x + mrg[(i * 4 + 0) * 128 + jc], 0.6f * (Ai + Bj.x));
            float a1 = fmaf(0.4f, acc[i].y + mrg[(i * 4 + 1) * 128 + jc], 0.6f * (Ai + Bj.y));
            float a2 = fmaf(0.4f, acc[i].z + mrg[(i * 4 + 2) * 128 + jc], 0.6f * (Ai + Bj.z));
            float a3 = fmaf(0.4f, acc[i].w + mrg[(i * 4 + 3) * 128 + jc], 0.6f * (Ai + Bj.w));
            if (!isfinite(a0)) a0 = 0.f;   // nan_to_num
            if (!isfinite(a1)) a1 = 0.f;
            if (!isfinite(a2)) a2 = 0.f;
            if (!isfinite(a3)) a3 = 0.f;
            *(float4*)&alph[i * 512 + jc * 4] = make_float4(a0, a1, a2, a3);
        }
    }
    __syncthreads();

    // top-20 + softmax: waves 0,1 handle rows 0,1
    if (tid >= 128) return;
    const int lane = tid & 63;
    const int i = tid >> 6;
    const float* ar = &alph[i * 512];
    const float4 u0 = *(const float4*)&ar[lane * 8];
    const float4 u1 = *(const float4*)&ar[lane * 8 + 4];
    float v[8] = {u0.x, u0.y, u0.z, u0.w, u1.x, u1.y, u1.z, u1.w};  // j = lane*8 + t

    float myval = 0.f, mmax = 0.f;
    int myidx = 0;
    for (int sel = 0; sel < 20; ++sel) {
        float bv = v[0]; int bt = 0;
#pragma unroll
        for (int t = 1; t < 8; ++t) { if (v[t] > bv) { bv = v[t]; bt = t; } }
        int bj = lane * 8 + bt;
#pragma unroll
        for (int off = 32; off; off >>= 1) {   // butterfly argmax, lower j wins ties
            const float ov = __shfl_xor(bv, off);
            const int   oj = __shfl_xor(bj, off);
            if (ov > bv || (ov == bv && oj < bj)) { bv = ov; bj = oj; }
        }
        if (sel == 0) mmax = bv;
        if (lane == sel) { myval = bv; myidx = bj; }
        if ((bj >> 3) == lane) {
            const int bt2 = bj & 7;
#pragma unroll
            for (int t = 0; t < 8; ++t) if (t == bt2) v[t] = -INFINITY;
        }
    }
    const float e = (lane < 20) ? expf(myval - mmax) : 0.f;
    float s = e;
#pragma unroll
    for (int off = 32; off; off >>= 1) s += __shfl_xor(s, off);
    if (lane < 20) {
        const int row = R + i;
        const int base = row * 20 + lane;
        out[base] = (float)row;                        // index_i
        out[40960 + base] = (float)(b * 512 + myidx);  // index_j
        out[81920 + base] = e / s;                     // attention
    }
}

extern "C" void kernel_launch(void* const* d_in, const int* in_sizes, int n_in,
                              void* d_out, int out_size, void* d_ws, size_t ws_size,
                              hipStream_t stream) {
    const float* x   = (const float*)d_in[0];
    const float* Wl  = (const float*)d_in[3];
    const float* bl  = (const float*)d_in[4];
    const float* Wr  = (const float*)d_in[5];
    const float* br  = (const float*)d_in[6];
    const float* att = (const float*)d_in[7];

    float* ws    = (float*)d_ws;
    float* WtL   = ws;
    float* WtR   = ws + 65536;
    float* XL    = ws + 1048576;
    float* XRt   = ws + 1572864;
    float* Av    = ws + 2097152;
    float* Bv    = ws + 2099200;
    float* out   = (float*)d_out;

    k_transpose<<<dim3(256, 2), dim3(256), 0, stream>>>(Wl, Wr, WtL, WtR);
    k_proj<<<dim3(256), dim3(1024), 0, stream>>>(x, WtL, WtR, bl, br, att, XL, XRt, Av, Bv);
    k_pair_topk<<<dim3(1024), dim3(256), 0, stream>>>(XL, XRt, Av, Bv, att, out);
}